// Round 1
// baseline (625.038 us; speedup 1.0000x reference)
//
#include <hip/hip_runtime.h>

// 8-bit ripple-carry adder on {0,1} floats.
// Memory-bound: ~872 MB total traffic -> ~138 us floor @ 6.3 TB/s.
// One thread per row: 2x float4 loads for A and B, exact float carry chain,
// 2x float4 stores for sums + 1 float carry store.

__global__ __launch_bounds__(256) void Adder8Bit_kernel(
    const float4* __restrict__ A4,   // [N*2] float4 view of A[N,8]
    const float4* __restrict__ B4,   // [N*2]
    const float*  __restrict__ Cin,  // [N]
    float4*       __restrict__ S4,   // [N*2] sums output
    float*        __restrict__ Cout, // [N]   carry output
    int N)
{
    int i = blockIdx.x * blockDim.x + threadIdx.x;
    if (i >= N) return;

    float4 a0 = A4[2 * i];
    float4 a1 = A4[2 * i + 1];
    float4 b0 = B4[2 * i];
    float4 b1 = B4[2 * i + 1];
    float c = Cin[i];

    float a[8] = {a0.x, a0.y, a0.z, a0.w, a1.x, a1.y, a1.z, a1.w};
    float b[8] = {b0.x, b0.y, b0.z, b0.w, b1.x, b1.y, b1.z, b1.w};
    float s[8];

    // Ripple from bit 7 (LSB) down to bit 0 (MSB) — same arithmetic as ref.
    #pragma unroll
    for (int k = 7; k >= 0; --k) {
        float ab = a[k] * b[k];
        float x  = a[k] + b[k] - 2.0f * ab;   // a xor b
        s[k]     = x + c - 2.0f * x * c;      // (a xor b) xor c
        c        = ab + c * x;                // carry out
    }

    S4[2 * i]     = make_float4(s[0], s[1], s[2], s[3]);
    S4[2 * i + 1] = make_float4(s[4], s[5], s[6], s[7]);
    Cout[i] = c;
}

extern "C" void kernel_launch(void* const* d_in, const int* in_sizes, int n_in,
                              void* d_out, int out_size, void* d_ws, size_t ws_size,
                              hipStream_t stream) {
    const float* A   = (const float*)d_in[0];   // [N,8]
    const float* B   = (const float*)d_in[1];   // [N,8]
    const float* Cin = (const float*)d_in[2];   // [N,1]
    float* out = (float*)d_out;                 // [N*8] sums ++ [N] carry

    const int N = in_sizes[0] / 8;

    float4* S4   = (float4*)out;
    float*  Cout = out + (size_t)8 * N;

    const int block = 256;
    const int grid  = (N + block - 1) / block;

    Adder8Bit_kernel<<<grid, block, 0, stream>>>(
        (const float4*)A, (const float4*)B, Cin, S4, Cout, N);
}

// Round 2
// 619.812 us; speedup vs baseline: 1.0084x; 1.0084x over previous
//
#include <hip/hip_runtime.h>

// 8-bit ripple-carry adder on {0,1} floats, bitwise formulation.
// Inputs are exactly 0.0f (0x00000000) or 1.0f (0x3F800000), so boolean
// logic on the raw uint32 patterns reproduces the reference's exact {0,1}
// float outputs bit-for-bit:  s = a^b^c ; cout = (a&b)|(c&(a^b)).
//
// Layout: one HALF-ROW (4 columns = one uint4) per thread -> every A/B/S
// vmem instruction is a perfectly dense dwordx4 (16 B/lane, lane-contiguous),
// unlike the R1 one-row-per-thread version whose 32-B lane stride scattered
// each wave access across 2x the cache lines (measured 3.0 TB/s, 37% peak).
//
// Thread t: row r = t>>1. t odd  -> columns 4..7 (contains bit 7 = LSB).
//           t even -> columns 0..3 (MSB side, produces final carry).
// Ripple order is bit 7 -> bit 0, i.e. component .w,.z,.y,.x in each half;
// odd lane's carry-out reaches its even partner via __shfl_xor(...,1).

__device__ __forceinline__ unsigned fa(unsigned a, unsigned b, unsigned c,
                                       unsigned& s) {
    unsigned x = a ^ b;
    s = x ^ c;
    return (a & b) | (c & x);
}

__global__ __launch_bounds__(256) void Adder8Bit_kernel(
    const uint4* __restrict__ A4,   // [2N] dense uint4 view of A[N,8]
    const uint4* __restrict__ B4,   // [2N]
    const unsigned* __restrict__ Cin,  // [N]
    uint4*       __restrict__ S4,   // [2N] sums output
    unsigned*    __restrict__ Cout, // [N]  carry output
    int halves)                      // = 2N
{
    int t = blockIdx.x * blockDim.x + threadIdx.x;
    if (t >= halves) return;

    int r     = t >> 1;
    int isLSB = t & 1;  // lane parity == t parity (block multiple of 64)

    uint4 a = A4[t];
    uint4 b = B4[t];
    unsigned cin0 = Cin[r];

    // Phase 1: chain over my 4 columns with cin = Cin[r].
    // (Only the LSB half's carry-out is meaningful.)
    uint4 s1;
    unsigned c = cin0;
    c = fa(a.w, b.w, c, s1.w);
    c = fa(a.z, b.z, c, s1.z);
    c = fa(a.y, b.y, c, s1.y);
    c = fa(a.x, b.x, c, s1.x);

    // Even (MSB) lane fetches its odd partner's carry-out.
    unsigned cprev = (unsigned)__shfl_xor((int)c, 1);

    // Phase 2: redo with the correct carry-in (same value for LSB lanes).
    unsigned cin = isLSB ? cin0 : cprev;
    uint4 s2;
    c = cin;
    c = fa(a.w, b.w, c, s2.w);
    c = fa(a.z, b.z, c, s2.z);
    c = fa(a.y, b.y, c, s2.y);
    c = fa(a.x, b.x, c, s2.x);

    S4[t] = s2;
    if (!isLSB) Cout[r] = c;  // overall carry comes from the MSB half
}

extern "C" void kernel_launch(void* const* d_in, const int* in_sizes, int n_in,
                              void* d_out, int out_size, void* d_ws, size_t ws_size,
                              hipStream_t stream) {
    const unsigned* A   = (const unsigned*)d_in[0];  // [N,8]
    const unsigned* B   = (const unsigned*)d_in[1];  // [N,8]
    const unsigned* Cin = (const unsigned*)d_in[2];  // [N,1]
    unsigned* out = (unsigned*)d_out;                // [8N] sums ++ [N] carry

    const int N      = in_sizes[0] / 8;
    const int halves = 2 * N;

    uint4*    S4   = (uint4*)out;
    unsigned* Cout = out + (size_t)8 * N;

    const int block = 256;
    const int grid  = (halves + block - 1) / block;

    Adder8Bit_kernel<<<grid, block, 0, stream>>>(
        (const uint4*)A, (const uint4*)B, Cin, S4, Cout, halves);
}